// Round 9
// baseline (534.184 us; speedup 1.0000x reference)
//
#include <hip/hip_runtime.h>
#include <hip/hip_cooperative_groups.h>
#include <hip/hip_fp16.h>
#include <math.h>

namespace cg = cooperative_groups;

#define N_NODES 50000
#define N_EDGES 800000
#define D 128
#define L 3
#define SLOPE 0.2f
#define LN_EPS 1e-5f
#define ETOT (N_EDGES + N_NODES)
#define SCAN_BLOCKS ((N_NODES + 1023) / 1024)   // 49

typedef _Float16 half8 __attribute__((ext_vector_type(8)));
typedef _Float16 h4v  __attribute__((ext_vector_type(4)));
typedef _Float16 h2v  __attribute__((ext_vector_type(2)));
typedef float f32x4 __attribute__((ext_vector_type(4)));

// ---------------- CSR build (once per call, reused for all layers) ----------

__global__ void rank_hist_kernel(const int* __restrict__ ei, int* __restrict__ counts,
                                 int* __restrict__ rank) {
    int idx = blockIdx.x * blockDim.x + threadIdx.x;
    if (idx >= ETOT) return;
    int d = (idx < N_EDGES) ? ei[N_EDGES + idx] : (idx - N_EDGES);
    rank[idx] = atomicAdd(&counts[d], 1);
}

// scan1 also builds the per-block degree histogram (fused deg_hist).
__global__ __launch_bounds__(1024) void scan1_kernel(const int* __restrict__ counts,
                                                     int* __restrict__ offsets,
                                                     int* __restrict__ bsum,
                                                     int* __restrict__ blockhist) {
    __shared__ int wsum[16];
    __shared__ int lh[256];
    int tid = threadIdx.x;
    if (tid < 256) lh[tid] = 0;
    __syncthreads();
    int lane = tid & 63, w = tid >> 6;
    int i = blockIdx.x * 1024 + tid;
    int v = (i < N_NODES) ? counts[i] : 0;
    if (i < N_NODES) {
        int d = v; if (d > 255) d = 255;
        atomicAdd(&lh[d], 1);                  // LDS histogram, cheap
    }
    int sc = v;
    #pragma unroll
    for (int off = 1; off < 64; off <<= 1) {
        int u = __shfl_up(sc, off);
        if (lane >= off) sc += u;
    }
    if (lane == 63) wsum[w] = sc;
    __syncthreads();
    if (w == 0) {
        int t2 = (lane < 16) ? wsum[lane] : 0;
        #pragma unroll
        for (int off = 1; off < 16; off <<= 1) {
            int u = __shfl_up(t2, off);
            if (lane >= off) t2 += u;
        }
        if (lane < 16) wsum[lane] = t2;
    }
    __syncthreads();
    int wpref = (w == 0) ? 0 : wsum[w - 1];
    if (i < N_NODES) offsets[i] = wpref + sc - v;      // block-local exclusive
    if (tid == 0) bsum[blockIdx.x] = wsum[15];
    __syncthreads();
    if (tid < 256) blockhist[blockIdx.x * 256 + tid] = lh[tid];
}

// scan2 also turns blockhist into global scatter bases (fused deg_scan).
__global__ __launch_bounds__(256) void scan2_kernel(const int* __restrict__ bsum,
                                                    int* __restrict__ bpre,
                                                    int* __restrict__ blockhist) {
    int tid = threadIdx.x;
    if (tid < 64) {
        int lane = tid;
        int v = (lane < SCAN_BLOCKS) ? bsum[lane] : 0;
        int sc = v;
        #pragma unroll
        for (int off = 1; off < 64; off <<= 1) {
            int u = __shfl_up(sc, off);
            if (lane >= off) sc += u;
        }
        if (lane < SCAN_BLOCKS) bpre[lane] = sc - v;   // exclusive
    }
    int d = tid;
    int run = 0;
    #pragma unroll 1
    for (int b = 0; b < SCAN_BLOCKS; ++b) {
        int c = blockhist[b * 256 + d];
        blockhist[b * 256 + d] = run;
        run += c;
    }
    __shared__ int wsum[4];
    int lane = d & 63, w = d >> 6;
    int sc = run;
    #pragma unroll
    for (int off = 1; off < 64; off <<= 1) {
        int u = __shfl_up(sc, off);
        if (lane >= off) sc += u;
    }
    if (lane == 63) wsum[w] = sc;
    __syncthreads();
    int wpre = 0;
    #pragma unroll
    for (int k = 0; k < 4; ++k) wpre += (k < w) ? wsum[k] : 0;
    int binbase = wpre + sc - run;                  // exclusive over bins
    #pragma unroll 1
    for (int b = 0; b < SCAN_BLOCKS; ++b)
        blockhist[b * 256 + d] += binbase;
}

// scan3 also scatters the degree-sorted node permutation (fused deg_scatter).
__global__ __launch_bounds__(1024) void scan3_kernel(int* __restrict__ offsets,
                                                     const int* __restrict__ bpre,
                                                     const int* __restrict__ counts,
                                                     const int* __restrict__ blockhist,
                                                     int* __restrict__ perm) {
    __shared__ int lh[256];
    int tid = threadIdx.x;
    if (tid < 256) lh[tid] = 0;
    __syncthreads();
    int i = blockIdx.x * 1024 + tid;
    if (i < N_NODES) {
        offsets[i] += bpre[blockIdx.x];
        int d = counts[i]; if (d > 255) d = 255;
        int r = atomicAdd(&lh[d], 1);               // LDS rank within block+bin
        perm[blockhist[blockIdx.x * 256 + d] + r] = i;
    }
    if (i == 0) offsets[N_NODES] = ETOT;
}

__global__ void scatter_kernel(const int* __restrict__ ei, const int* __restrict__ offsets,
                               const int* __restrict__ rank,
                               unsigned short* __restrict__ sorted16) {
    int idx = blockIdx.x * blockDim.x + threadIdx.x;
    if (idx >= ETOT) return;
    int s, d;
    if (idx < N_EDGES) { s = ei[idx]; d = ei[N_EDGES + idx]; }
    else               { s = d = idx - N_EDGES; }
    sorted16[offsets[d] + rank[idx]] = (unsigned short)s;   // no atomic
}

// ---------------- W -> fp16 MFMA B-fragment precompute ---------------------

__global__ __launch_bounds__(256) void wfrag_kernel(const float* __restrict__ Wl,
                                                    const float* __restrict__ Wr,
                                                    _Float16* __restrict__ Wfrag) {
    int u = blockIdx.x * 256 + threadIdx.x;   // 3*2*4*8*64 = 12288 slots
    if (u >= 3 * 4096) return;
    int lane = u & 63, nt = (u >> 6) & 7, kt = (u >> 9) & 3, y = (u >> 11) & 1, l = u >> 12;
    int r = lane & 15, q = lane >> 4;
    const float* W = (y ? Wr : Wl) + (size_t)l * D * D;
    half8 v;
    #pragma unroll
    for (int j = 0; j < 8; ++j)
        v[j] = (_Float16)W[(kt * 32 + q * 8 + j) * D + nt * 16 + r];
    *(half8*)&Wfrag[(size_t)u * 8] = v;
}

// ---------------- helpers for the fused layer kernel -----------------------

__device__ __forceinline__ float pair_reduce2(float p) {
    int t;
    t = __builtin_amdgcn_update_dpp(0, __float_as_int(p), 0xB1, 0xF, 0xF, true);  // quad [1,0,3,2]
    p += __int_as_float(t);
    return p;
}

__device__ __forceinline__ float logit8(half8 v, half8 xr, const h2v* att4, h2v slope2) {
    float p = 0.f;
    #pragma unroll
    for (int i = 0; i < 4; ++i) {
        h2v a; a[0] = v[2 * i];  a[1] = v[2 * i + 1];
        h2v b; b[0] = xr[2 * i]; b[1] = xr[2 * i + 1];
        h2v f  = a + b;                                   // v_pk_add_f16
        h2v lf = __builtin_elementwise_max(f, f * slope2);
        p = __builtin_amdgcn_fdot2(lf, att4[i], p, false);
    }
    return p;
}

template<int KUN, bool MASK>
__device__ __forceinline__ void edge_block(
        int j, int idx_bp, unsigned off, unsigned laneoff, const char* xlb,
        half8 xr8, const h2v* att4, h2v slope2, int cnt,
        float& s, float* acc) {
    half8 vs[KUN];
    #pragma unroll
    for (int k = 0; k < KUN; ++k) {
        int o = __builtin_amdgcn_ds_bpermute(idx_bp + 4 * (j + k), (int)off);
        vs[k] = *(const half8*)(xlb + ((unsigned)o + laneoff));   // dwordx4
    }
    #pragma unroll
    for (int k = 0; k < KUN; ++k) {
        float p = logit8(vs[k], xr8, att4, slope2);
        p = pair_reduce2(p);
        float e = __builtin_amdgcn_exp2f(p);
        if (MASK) e = (j + k < cnt) ? e : 0.f;
        s += e;
        #pragma unroll
        for (int i = 0; i < 8; ++i)
            acc[i] = fmaf(e, (float)vs[k][i], acc[i]);            // v_fma_mix
    }
}

// ---------------- FUSED layer kernel: GEMM phase + grid.sync + GAT phase ---
// Cooperative launch; grid sized via occupancy API so all blocks co-resident.
// Phase 1: tile-strided MFMA GEMM (round-8 body, operand-swapped stores).
// Phase 2: slot-strided per-node GATv2 (round-8 body, LPT order).

template<bool AHALF>
__global__ __launch_bounds__(256) void layer_fused_kernel(
        const void* __restrict__ hsrc, const _Float16* __restrict__ WfragL,
        _Float16* __restrict__ xlh, _Float16* __restrict__ xrh,
        const int* __restrict__ offsets, const unsigned short* __restrict__ sorted16,
        const int* __restrict__ perm,
        const float* __restrict__ att_l, const float* __restrict__ bias_l,
        const float* __restrict__ gamma_l, const float* __restrict__ beta_l,
        const float* __restrict__ hin, float* __restrict__ hout,
        _Float16* __restrict__ h16out) {
    __shared__ half8 Afrag[1024];   // [ntile][kt][lane], 16 KB
    int t = threadIdx.x;

    // ================= phase 1: GEMM =================
    {
        int w = t >> 6, lane = t & 63;
        int y = w >> 1, nh = w & 1;     // wave's W-matrix (l/r) and feature half
        const int NT = (N_NODES + 63) / 64;    // 782
        bool first = true;
        for (int tile = blockIdx.x; tile < NT; tile += gridDim.x) {
            int row0 = tile * 64;
            half8 bfrag[16];            // [kt][f], compile-time indexed only
            #pragma unroll
            for (int kt = 0; kt < 4; ++kt)
                #pragma unroll
                for (int f = 0; f < 4; ++f) {
                    int nt = nh * 4 + f;
                    bfrag[kt * 4 + f] =
                        *(const half8*)&WfragL[(size_t)(((y * 4 + kt) * 8 + nt) * 64 + lane) * 8];
                }
            if (!first) __syncthreads();    // protect Afrag from prev tile's readers
            first = false;
            {
                int kt = t >> 6, q = (t >> 4) & 3, r = t & 15;
                int kc = kt * 4 + q;                  // 8-half chunk index
                #pragma unroll
                for (int i = 0; i < 4; ++i) {
                    int row = row0 + i * 16 + r;
                    half8 v = {};
                    if (row < N_NODES) {
                        if constexpr (AHALF) {
                            const _Float16* h16 = (const _Float16*)hsrc;
                            v = *(const half8*)&h16[(size_t)row * D + kc * 8];
                        } else {
                            const float* p = &((const float*)hsrc)[(size_t)row * D + kc * 8];
                            float4 f0 = *(const float4*)p;
                            float4 f1 = *(const float4*)(p + 4);
                            v[0] = (_Float16)f0.x; v[1] = (_Float16)f0.y;
                            v[2] = (_Float16)f0.z; v[3] = (_Float16)f0.w;
                            v[4] = (_Float16)f1.x; v[5] = (_Float16)f1.y;
                            v[6] = (_Float16)f1.z; v[7] = (_Float16)f1.w;
                        }
                    }
                    Afrag[i * 256 + t] = v;           // [ntile][kt*64 + q*16 + r]
                }
            }
            __syncthreads();
            f32x4 acc[16];              // [f][ntile]
            #pragma unroll
            for (int i = 0; i < 16; ++i) acc[i] = (f32x4){0.f, 0.f, 0.f, 0.f};
            #pragma unroll
            for (int ntile = 0; ntile < 4; ++ntile) {
                #pragma unroll
                for (int kt = 0; kt < 4; ++kt) {
                    half8 a = Afrag[ntile * 256 + kt * 64 + lane];
                    #pragma unroll
                    for (int f = 0; f < 4; ++f)
                        acc[f * 4 + ntile] = __builtin_amdgcn_mfma_f32_16x16x32_f16(
                            bfrag[kt * 4 + f], a, acc[f * 4 + ntile], 0, 0, 0);
                }
            }
            _Float16* out = y ? xrh : xlh;
            int nr = lane & 15, fq = lane >> 4;
            #pragma unroll
            for (int ntile = 0; ntile < 4; ++ntile) {
                int row = row0 + ntile * 16 + nr;
                if (row < N_NODES) {
                    #pragma unroll
                    for (int f = 0; f < 4; ++f) {
                        int fb = nh * 64 + f * 16 + fq * 4;
                        h4v v4;
                        v4[0] = (_Float16)acc[f * 4 + ntile][0];
                        v4[1] = (_Float16)acc[f * 4 + ntile][1];
                        v4[2] = (_Float16)acc[f * 4 + ntile][2];
                        v4[3] = (_Float16)acc[f * 4 + ntile][3];
                        *(h4v*)&out[(size_t)row * D + fb] = v4;
                    }
                }
            }
        }
    }

    cg::this_grid().sync();             // xl/xr visible device-wide

    // ================= phase 2: GAT =================
    int lane = threadIdx.x & 63;
    int g = lane >> 4, hl = lane & 15;         // group (node select), sub-lane
    unsigned laneoff = hl * 16u;
    int idx_bp = g << 6;

    // hl-dependent invariants hoisted out of the slot loop
    float4 af0 = *(const float4*)&att_l[hl * 8];
    float4 af1 = *(const float4*)&att_l[hl * 8 + 4];
    h2v att4[4], slope2;
    att4[0][0] = (_Float16)(af0.x * 1.44269504f);  // pre-scale by log2(e)
    att4[0][1] = (_Float16)(af0.y * 1.44269504f);
    att4[1][0] = (_Float16)(af0.z * 1.44269504f);
    att4[1][1] = (_Float16)(af0.w * 1.44269504f);
    att4[2][0] = (_Float16)(af1.x * 1.44269504f);
    att4[2][1] = (_Float16)(af1.y * 1.44269504f);
    att4[3][0] = (_Float16)(af1.z * 1.44269504f);
    att4[3][1] = (_Float16)(af1.w * 1.44269504f);
    slope2[0] = (_Float16)SLOPE;
    slope2[1] = (_Float16)SLOPE;
    float4 b0 = *(const float4*)&bias_l[hl * 8];
    float4 b1 = *(const float4*)&bias_l[hl * 8 + 4];
    float4 gm0 = *(const float4*)&gamma_l[hl * 8];
    float4 gm1 = *(const float4*)&gamma_l[hl * 8 + 4];
    float4 bt0 = *(const float4*)&beta_l[hl * 8];
    float4 bt1 = *(const float4*)&beta_l[hl * 8 + 4];
    const char* xlb = (const char*)xlh;

    int slot0 = (blockIdx.x * 256 + threadIdx.x) >> 6;
    int nw = gridDim.x * 4;
    const int NG = N_NODES / 4;               // 12500

    for (int slot = slot0; slot < NG; slot += nw) {
        int node = perm[N_NODES - 4 - slot * 4 + g];   // LPT: descending degree

        half8 xr8 = *(const half8*)&xrh[(size_t)node * D + hl * 8];
        int beg = offsets[node], end = offsets[node + 1];
        int deg = end - beg;                                 // uniform per group
        int d0 = __builtin_amdgcn_readlane(deg, 0);
        int d1 = __builtin_amdgcn_readlane(deg, 16);
        int d2 = __builtin_amdgcn_readlane(deg, 32);
        int d3 = __builtin_amdgcn_readlane(deg, 48);
        int m01 = d0 > d1 ? d0 : d1, m23 = d2 > d3 ? d2 : d3;
        int degMax = m01 > m23 ? m01 : m23;
        int n01 = d0 < d1 ? d0 : d1, n23 = d2 < d3 ? d2 : d3;
        int degMin = n01 < n23 ? n01 : n23;

        float s = 0.f;
        float acc[8] = {0.f, 0.f, 0.f, 0.f, 0.f, 0.f, 0.f, 0.f};

        for (int c0 = 0; c0 < degMax; c0 += 16) {
            int rem = deg - c0;
            int cnt = rem > 16 ? 16 : rem;
            int cl  = cnt > 0 ? (hl < cnt ? hl : cnt - 1) : 0;
            int pos = cnt > 0 ? beg + c0 + cl : beg;         // clamped, in-bounds
            unsigned off = ((unsigned)sorted16[pos]) << 8;   // fp16 row byte offset
            int jmax = degMax - c0; if (jmax > 16) jmax = 16;
            int nfull = degMin - c0; if (nfull > 16) nfull = 16; if (nfull < 0) nfull = 0;
            int j = 0;
            for (; j + 8 <= nfull; j += 8)
                edge_block<8, false>(j, idx_bp, off, laneoff, xlb, xr8, att4, slope2,
                                     cnt, s, acc);
            for (; j + 4 <= nfull; j += 4)
                edge_block<4, false>(j, idx_bp, off, laneoff, xlb, xr8, att4, slope2,
                                     cnt, s, acc);
            for (; j + 4 <= jmax; j += 4)
                edge_block<4, true>(j, idx_bp, off, laneoff, xlb, xr8, att4, slope2,
                                    cnt, s, acc);
            for (; j < jmax; ++j)
                edge_block<1, true>(j, idx_bp, off, laneoff, xlb, xr8, att4, slope2,
                                    cnt, s, acc);
        }

        float inv = 1.f / s;             // every node has >=1 edge (self-loop)
        float o[8];
        o[0] = acc[0] * inv + b0.x; o[1] = acc[1] * inv + b0.y;
        o[2] = acc[2] * inv + b0.z; o[3] = acc[3] * inv + b0.w;
        o[4] = acc[4] * inv + b1.x; o[5] = acc[5] * inv + b1.y;
        o[6] = acc[6] * inv + b1.z; o[7] = acc[7] * inv + b1.w;
        float sum = ((o[0] + o[1]) + (o[2] + o[3])) + ((o[4] + o[5]) + (o[6] + o[7]));
        float sq  = ((o[0] * o[0] + o[1] * o[1]) + (o[2] * o[2] + o[3] * o[3]))
                  + ((o[4] * o[4] + o[5] * o[5]) + (o[6] * o[6] + o[7] * o[7]));
        #pragma unroll
        for (int msk = 1; msk < 16; msk <<= 1) {   // stays inside 16-lane group
            sum += __shfl_xor(sum, msk);
            sq  += __shfl_xor(sq, msk);
        }
        float mu   = sum * (1.f / 128.f);
        float var  = sq * (1.f / 128.f) - mu * mu;
        float rstd = rsqrtf(var + LN_EPS);
        size_t di = (size_t)node * D + hl * 8;
        float4 h0 = *(const float4*)&hin[di];
        float4 h1 = *(const float4*)&hin[di + 4];
        float hv[8] = {h0.x, h0.y, h0.z, h0.w, h1.x, h1.y, h1.z, h1.w};
        float gam[8] = {gm0.x, gm0.y, gm0.z, gm0.w, gm1.x, gm1.y, gm1.z, gm1.w};
        float bet[8] = {bt0.x, bt0.y, bt0.z, bt0.w, bt1.x, bt1.y, bt1.z, bt1.w};
        float yv[8];
        #pragma unroll
        for (int i = 0; i < 8; ++i) {
            float tt = (o[i] - mu) * rstd * gam[i] + bet[i];
            tt = tt > 0.f ? tt : __expf(tt) - 1.f;   // ELU (alpha=1)
            yv[i] = hv[i] + tt;
        }
        float4 w0 = make_float4(yv[0], yv[1], yv[2], yv[3]);
        float4 w1 = make_float4(yv[4], yv[5], yv[6], yv[7]);
        *(float4*)&hout[di]     = w0;
        *(float4*)&hout[di + 4] = w1;
        half8 h16v;
        #pragma unroll
        for (int i = 0; i < 8; ++i) h16v[i] = (_Float16)yv[i];
        *(half8*)&h16out[di] = h16v;     // fp16 copy for next layer's gemm
    }
}

// ---------------------------------------------------------------------------

extern "C" void kernel_launch(void* const* d_in, const int* in_sizes, int n_in,
                              void* d_out, int out_size, void* d_ws, size_t ws_size,
                              hipStream_t stream) {
    const float* x     = (const float*)d_in[0];
    const float* Wl    = (const float*)d_in[1];
    const float* Wr    = (const float*)d_in[2];
    const float* att   = (const float*)d_in[3];
    const float* bias  = (const float*)d_in[4];
    const float* gamma = (const float*)d_in[5];
    const float* beta  = (const float*)d_in[6];
    const int*   ei    = (const int*)d_in[7];
    float* h = (float*)d_out;

    char* ws = (char*)d_ws;
    _Float16* xlh = (_Float16*)ws;   ws += (size_t)N_NODES * D * sizeof(_Float16);
    _Float16* xrh = (_Float16*)ws;   ws += (size_t)N_NODES * D * sizeof(_Float16);
    _Float16* h16 = (_Float16*)ws;   ws += (size_t)N_NODES * D * sizeof(_Float16);
    _Float16* Wfrag = (_Float16*)ws; ws += (size_t)3 * 4096 * 8 * sizeof(_Float16);
    int* offsets = (int*)ws;         ws += (size_t)(N_NODES + 4) * sizeof(int);
    int* counts  = (int*)ws;         ws += (size_t)N_NODES * sizeof(int);
    int* bsum    = (int*)ws;         ws += 64 * sizeof(int);
    int* bpre    = (int*)ws;         ws += 64 * sizeof(int);
    int* blockhist = (int*)ws;       ws += (size_t)SCAN_BLOCKS * 256 * sizeof(int);
    int* perm    = (int*)ws;         ws += (size_t)N_NODES * sizeof(int);
    int* rank    = (int*)ws;         ws += (size_t)ETOT * sizeof(int);
    unsigned short* sorted16 = (unsigned short*)ws;   // ETOT u16

    // cooperative grid sizing (cached; host-side queries only, capture-safe)
    static int grid_f = 0, grid_t = 0;
    if (grid_t == 0) {
        hipDeviceProp_t prop;
        (void)hipGetDeviceProperties(&prop, 0);
        int mbF = 0, mbT = 0;
        (void)hipOccupancyMaxActiveBlocksPerMultiprocessor(
            &mbF, (const void*)layer_fused_kernel<false>, 256, 0);
        (void)hipOccupancyMaxActiveBlocksPerMultiprocessor(
            &mbT, (const void*)layer_fused_kernel<true>, 256, 0);
        if (mbF < 1) mbF = 1;
        if (mbT < 1) mbT = 1;
        grid_f = mbF * prop.multiProcessorCount;
        grid_t = mbT * prop.multiProcessorCount;
    }

    // W fragments + CSR by dst + degree-sort perm (shared by all 3 layers)
    wfrag_kernel<<<48, 256, 0, stream>>>(Wl, Wr, Wfrag);
    (void)hipMemsetAsync(counts, 0, (size_t)N_NODES * sizeof(int), stream);
    rank_hist_kernel<<<(ETOT + 255) / 256, 256, 0, stream>>>(ei, counts, rank);
    scan1_kernel<<<SCAN_BLOCKS, 1024, 0, stream>>>(counts, offsets, bsum, blockhist);
    scan2_kernel<<<1, 256, 0, stream>>>(bsum, bpre, blockhist);
    scan3_kernel<<<SCAN_BLOCKS, 1024, 0, stream>>>(offsets, bpre, counts, blockhist, perm);
    scatter_kernel<<<(ETOT + 255) / 256, 256, 0, stream>>>(ei, offsets, rank, sorted16);

    for (int l = 0; l < L; ++l) {
        const void* hsrc = (l == 0) ? (const void*)x : (const void*)h16;
        const _Float16* wf = Wfrag + (size_t)l * 4096 * 8;
        const float* attp   = att + (size_t)l * D;
        const float* biasp  = bias + (size_t)l * D;
        const float* gammap = gamma + (size_t)l * D;
        const float* betap  = beta + (size_t)l * D;
        const float* hinp   = (l == 0) ? x : h;
        const int* offp = offsets;
        const unsigned short* so = sorted16;
        const int* pp = perm;
        _Float16* xl_ = xlh; _Float16* xr_ = xrh;
        float* hp = h; _Float16* h16p = h16;
        void* args[14] = {&hsrc, &wf, &xl_, &xr_, &offp, &so, &pp,
                          &attp, &biasp, &gammap, &betap, &hinp, &hp, &h16p};
        if (l == 0)
            (void)hipLaunchCooperativeKernel(
                (const void*)layer_fused_kernel<false>, dim3(grid_f), dim3(256),
                args, 0, stream);
        else
            (void)hipLaunchCooperativeKernel(
                (const void*)layer_fused_kernel<true>, dim3(grid_t), dim3(256),
                args, 0, stream);
    }
}

// Round 10
// 326.691 us; speedup vs baseline: 1.6351x; 1.6351x over previous
//
#include <hip/hip_runtime.h>
#include <hip/hip_fp16.h>
#include <math.h>

#define N_NODES 50000
#define N_EDGES 800000
#define D 128
#define L 3
#define SLOPE 0.2f
#define LN_EPS 1e-5f
#define ETOT (N_EDGES + N_NODES)
#define SCAN_BLOCKS ((N_NODES + 1023) / 1024)   // 49

typedef _Float16 half8 __attribute__((ext_vector_type(8)));
typedef _Float16 h4v  __attribute__((ext_vector_type(4)));
typedef _Float16 h2v  __attribute__((ext_vector_type(2)));
typedef float f32x4 __attribute__((ext_vector_type(4)));

// ---------------- CSR build (once per call, reused for all layers) ----------

__global__ void rank_hist_kernel(const int* __restrict__ ei, int* __restrict__ counts,
                                 int* __restrict__ rank) {
    int idx = blockIdx.x * blockDim.x + threadIdx.x;
    if (idx >= ETOT) return;
    int d = (idx < N_EDGES) ? ei[N_EDGES + idx] : (idx - N_EDGES);
    rank[idx] = atomicAdd(&counts[d], 1);
}

// scan1 also builds the per-block degree histogram (fused deg_hist).
__global__ __launch_bounds__(1024) void scan1_kernel(const int* __restrict__ counts,
                                                     int* __restrict__ offsets,
                                                     int* __restrict__ bsum,
                                                     int* __restrict__ blockhist) {
    __shared__ int wsum[16];
    __shared__ int lh[256];
    int tid = threadIdx.x;
    if (tid < 256) lh[tid] = 0;
    __syncthreads();
    int lane = tid & 63, w = tid >> 6;
    int i = blockIdx.x * 1024 + tid;
    int v = (i < N_NODES) ? counts[i] : 0;
    if (i < N_NODES) {
        int d = v; if (d > 255) d = 255;
        atomicAdd(&lh[d], 1);                  // LDS histogram, cheap
    }
    int sc = v;
    #pragma unroll
    for (int off = 1; off < 64; off <<= 1) {
        int u = __shfl_up(sc, off);
        if (lane >= off) sc += u;
    }
    if (lane == 63) wsum[w] = sc;
    __syncthreads();
    if (w == 0) {
        int t2 = (lane < 16) ? wsum[lane] : 0;
        #pragma unroll
        for (int off = 1; off < 16; off <<= 1) {
            int u = __shfl_up(t2, off);
            if (lane >= off) t2 += u;
        }
        if (lane < 16) wsum[lane] = t2;
    }
    __syncthreads();
    int wpref = (w == 0) ? 0 : wsum[w - 1];
    if (i < N_NODES) offsets[i] = wpref + sc - v;      // block-local exclusive
    if (tid == 0) bsum[blockIdx.x] = wsum[15];
    __syncthreads();
    if (tid < 256) blockhist[blockIdx.x * 256 + tid] = lh[tid];
}

// scan2 also turns blockhist into global scatter bases (fused deg_scan).
__global__ __launch_bounds__(256) void scan2_kernel(const int* __restrict__ bsum,
                                                    int* __restrict__ bpre,
                                                    int* __restrict__ blockhist) {
    int tid = threadIdx.x;
    if (tid < 64) {
        int lane = tid;
        int v = (lane < SCAN_BLOCKS) ? bsum[lane] : 0;
        int sc = v;
        #pragma unroll
        for (int off = 1; off < 64; off <<= 1) {
            int u = __shfl_up(sc, off);
            if (lane >= off) sc += u;
        }
        if (lane < SCAN_BLOCKS) bpre[lane] = sc - v;   // exclusive
    }
    int d = tid;
    int run = 0;
    #pragma unroll 1
    for (int b = 0; b < SCAN_BLOCKS; ++b) {
        int c = blockhist[b * 256 + d];
        blockhist[b * 256 + d] = run;
        run += c;
    }
    __shared__ int wsum[4];
    int lane = d & 63, w = d >> 6;
    int sc = run;
    #pragma unroll
    for (int off = 1; off < 64; off <<= 1) {
        int u = __shfl_up(sc, off);
        if (lane >= off) sc += u;
    }
    if (lane == 63) wsum[w] = sc;
    __syncthreads();
    int wpre = 0;
    #pragma unroll
    for (int k = 0; k < 4; ++k) wpre += (k < w) ? wsum[k] : 0;
    int binbase = wpre + sc - run;                  // exclusive over bins
    #pragma unroll 1
    for (int b = 0; b < SCAN_BLOCKS; ++b)
        blockhist[b * 256 + d] += binbase;
}

// scan3 also scatters the degree-sorted node permutation (fused deg_scatter).
__global__ __launch_bounds__(1024) void scan3_kernel(int* __restrict__ offsets,
                                                     const int* __restrict__ bpre,
                                                     const int* __restrict__ counts,
                                                     const int* __restrict__ blockhist,
                                                     int* __restrict__ perm) {
    __shared__ int lh[256];
    int tid = threadIdx.x;
    if (tid < 256) lh[tid] = 0;
    __syncthreads();
    int i = blockIdx.x * 1024 + tid;
    if (i < N_NODES) {
        offsets[i] += bpre[blockIdx.x];
        int d = counts[i]; if (d > 255) d = 255;
        int r = atomicAdd(&lh[d], 1);               // LDS rank within block+bin
        perm[blockhist[blockIdx.x * 256 + d] + r] = i;
    }
    if (i == 0) offsets[N_NODES] = ETOT;
}

__global__ void scatter_kernel(const int* __restrict__ ei, const int* __restrict__ offsets,
                               const int* __restrict__ rank,
                               unsigned short* __restrict__ sorted16) {
    int idx = blockIdx.x * blockDim.x + threadIdx.x;
    if (idx >= ETOT) return;
    int s, d;
    if (idx < N_EDGES) { s = ei[idx]; d = ei[N_EDGES + idx]; }
    else               { s = d = idx - N_EDGES; }
    sorted16[offsets[d] + rank[idx]] = (unsigned short)s;   // no atomic
}

// ---------------- W -> fp16 MFMA B-fragment precompute ---------------------

__global__ __launch_bounds__(256) void wfrag_kernel(const float* __restrict__ Wl,
                                                    const float* __restrict__ Wr,
                                                    _Float16* __restrict__ Wfrag) {
    int u = blockIdx.x * 256 + threadIdx.x;   // 3*2*4*8*64 = 12288 slots
    if (u >= 3 * 4096) return;
    int lane = u & 63, nt = (u >> 6) & 7, kt = (u >> 9) & 3, y = (u >> 11) & 1, l = u >> 12;
    int r = lane & 15, q = lane >> 4;
    const float* W = (y ? Wr : Wl) + (size_t)l * D * D;
    half8 v;
    #pragma unroll
    for (int j = 0; j < 8; ++j)
        v[j] = (_Float16)W[(kt * 32 + q * 8 + j) * D + nt * 16 + r];
    *(half8*)&Wfrag[(size_t)u * 8] = v;
}

// ---------------- MFMA GEMM: xl,xr (fp16) = h @ {Wl,Wr} --------------------
// block = 4 waves; tile M=64, N=256. Wave owns (y, col-half); B(W) fragments
// register-resident. Operand-swapped MFMA: lane&15 = node row, 4 acc regs = 4
// consecutive features -> 8-B h4v stores.

template<bool AHALF>
__global__ __launch_bounds__(256) void gemm_mfma_kernel(
        const void* __restrict__ hsrc, const _Float16* __restrict__ WfragL,
        _Float16* __restrict__ xlh, _Float16* __restrict__ xrh) {
    __shared__ half8 Afrag[1024];   // [ntile][kt][lane], 16 KB
    int t = threadIdx.x;
    int row0 = blockIdx.x * 64;
    int w = t >> 6, lane = t & 63;
    int y = w >> 1, nh = w & 1;     // wave's W-matrix (l/r) and feature half

    // ---- W fragments: issue first (latency hidden under A staging) ----
    half8 bfrag[16];                // [kt][f], compile-time indexed only
    #pragma unroll
    for (int kt = 0; kt < 4; ++kt)
        #pragma unroll
        for (int f = 0; f < 4; ++f) {
            int nt = nh * 4 + f;
            bfrag[kt * 4 + f] =
                *(const half8*)&WfragL[(size_t)(((y * 4 + kt) * 8 + nt) * 64 + lane) * 8];
        }

    // ---- A staging: h tile -> fp16 fragments in LDS ----
    {
        int kt = t >> 6, q = (t >> 4) & 3, r = t & 15;
        int kc = kt * 4 + q;                  // 8-half chunk index
        #pragma unroll
        for (int i = 0; i < 4; ++i) {
            int row = row0 + i * 16 + r;
            half8 v = {};
            if (row < N_NODES) {
                if constexpr (AHALF) {
                    const _Float16* h16 = (const _Float16*)hsrc;
                    v = *(const half8*)&h16[(size_t)row * D + kc * 8];
                } else {
                    const float* p = &((const float*)hsrc)[(size_t)row * D + kc * 8];
                    float4 f0 = *(const float4*)p;
                    float4 f1 = *(const float4*)(p + 4);
                    v[0] = (_Float16)f0.x; v[1] = (_Float16)f0.y;
                    v[2] = (_Float16)f0.z; v[3] = (_Float16)f0.w;
                    v[4] = (_Float16)f1.x; v[5] = (_Float16)f1.y;
                    v[6] = (_Float16)f1.z; v[7] = (_Float16)f1.w;
                }
            }
            Afrag[i * 256 + t] = v;           // [ntile][kt*64 + q*16 + r]
        }
    }
    __syncthreads();

    // ---- compute: 4 node-tiles x 4 kt x 4 feature-tiles, operands swapped ----
    f32x4 acc[16];                  // [f][ntile]
    #pragma unroll
    for (int i = 0; i < 16; ++i) acc[i] = (f32x4){0.f, 0.f, 0.f, 0.f};
    #pragma unroll
    for (int ntile = 0; ntile < 4; ++ntile) {
        #pragma unroll
        for (int kt = 0; kt < 4; ++kt) {
            half8 a = Afrag[ntile * 256 + kt * 64 + lane];
            #pragma unroll
            for (int f = 0; f < 4; ++f)
                acc[f * 4 + ntile] = __builtin_amdgcn_mfma_f32_16x16x32_f16(
                    bfrag[kt * 4 + f], a, acc[f * 4 + ntile], 0, 0, 0);
        }
    }

    // ---- store: lane holds 4 consecutive feats of node ntile*16+(lane&15) ----
    _Float16* out = y ? xrh : xlh;
    int nr = lane & 15, fq = lane >> 4;
    #pragma unroll
    for (int ntile = 0; ntile < 4; ++ntile) {
        int row = row0 + ntile * 16 + nr;
        if (row < N_NODES) {
            #pragma unroll
            for (int f = 0; f < 4; ++f) {
                int fb = nh * 64 + f * 16 + fq * 4;
                h4v v4;
                v4[0] = (_Float16)acc[f * 4 + ntile][0];
                v4[1] = (_Float16)acc[f * 4 + ntile][1];
                v4[2] = (_Float16)acc[f * 4 + ntile][2];
                v4[3] = (_Float16)acc[f * 4 + ntile][3];
                *(h4v*)&out[(size_t)row * D + fb] = v4;
            }
        }
    }
}

// ---------------- per-node GATv2 + softmax + LN + ELU + residual -----------
// FOUR nodes per wave (degree-sorted, LPT descending dispatch).
// 16 lanes/node, 8 ch/lane; head = 2 lanes -> single DPP pair reduction;
// ds_bpermute edge-offset broadcast; dwordx4 gathers; KUN=8 (VGPR 64 ->
// 8 waves/SIMD residency, the measured lever for this latency-bound gather).
// NEW: c0-level software pipeline — block n+1's sorted16 row-offset load is
// issued BEFORE block n's gathers, hiding the serial sorted16->bpermute->load
// chain that dominates per-wave runtime.

__device__ __forceinline__ float pair_reduce2(float p) {
    int t;
    t = __builtin_amdgcn_update_dpp(0, __float_as_int(p), 0xB1, 0xF, 0xF, true);  // quad [1,0,3,2]
    p += __int_as_float(t);
    return p;
}

__device__ __forceinline__ float logit8(half8 v, half8 xr, const h2v* att4, h2v slope2) {
    float p = 0.f;
    #pragma unroll
    for (int i = 0; i < 4; ++i) {
        h2v a; a[0] = v[2 * i];  a[1] = v[2 * i + 1];
        h2v b; b[0] = xr[2 * i]; b[1] = xr[2 * i + 1];
        h2v f  = a + b;                                   // v_pk_add_f16
        h2v lf = __builtin_elementwise_max(f, f * slope2);
        p = __builtin_amdgcn_fdot2(lf, att4[i], p, false);
    }
    return p;
}

template<int KUN, bool MASK>
__device__ __forceinline__ void edge_block(
        int j, int idx_bp, unsigned off, unsigned laneoff, const char* xlb,
        half8 xr8, const h2v* att4, h2v slope2, int cnt,
        float& s, float* acc) {
    half8 vs[KUN];
    #pragma unroll
    for (int k = 0; k < KUN; ++k) {
        int o = __builtin_amdgcn_ds_bpermute(idx_bp + 4 * (j + k), (int)off);
        vs[k] = *(const half8*)(xlb + ((unsigned)o + laneoff));   // dwordx4
    }
    #pragma unroll
    for (int k = 0; k < KUN; ++k) {
        float p = logit8(vs[k], xr8, att4, slope2);
        p = pair_reduce2(p);
        float e = __builtin_amdgcn_exp2f(p);
        if (MASK) e = (j + k < cnt) ? e : 0.f;
        s += e;
        #pragma unroll
        for (int i = 0; i < 8; ++i)
            acc[i] = fmaf(e, (float)vs[k][i], acc[i]);            // v_fma_mix
    }
}

__global__ __launch_bounds__(256) void gat_node_kernel(
        const _Float16* __restrict__ xlh, const _Float16* __restrict__ xrh,
        const int* __restrict__ offsets, const unsigned short* __restrict__ sorted16,
        const int* __restrict__ perm,
        const float* __restrict__ att_l, const float* __restrict__ bias_l,
        const float* __restrict__ gamma_l, const float* __restrict__ beta_l,
        const float* __restrict__ hin, float* __restrict__ hout,
        _Float16* __restrict__ h16out) {
    int wid = (blockIdx.x * blockDim.x + threadIdx.x) >> 6;   // wave id
    if (wid * 4 >= N_NODES) return;
    int lane = threadIdx.x & 63;
    int g = lane >> 4, hl = lane & 15;         // group (node select), sub-lane
    int node = perm[N_NODES - 4 - wid * 4 + g];   // LPT: descending degree
    unsigned laneoff = hl * 16u;               // byte offset of this lane's 8 halves
    int idx_bp = g << 6;                       // bpermute byte base: lane 16*g

    half8 xr8 = *(const half8*)&xrh[(size_t)node * D + hl * 8];
    float4 af0 = *(const float4*)&att_l[hl * 8];
    float4 af1 = *(const float4*)&att_l[hl * 8 + 4];
    h2v att4[4], slope2;
    att4[0][0] = (_Float16)(af0.x * 1.44269504f);  // pre-scale by log2(e)
    att4[0][1] = (_Float16)(af0.y * 1.44269504f);
    att4[1][0] = (_Float16)(af0.z * 1.44269504f);
    att4[1][1] = (_Float16)(af0.w * 1.44269504f);
    att4[2][0] = (_Float16)(af1.x * 1.44269504f);
    att4[2][1] = (_Float16)(af1.y * 1.44269504f);
    att4[3][0] = (_Float16)(af1.z * 1.44269504f);
    att4[3][1] = (_Float16)(af1.w * 1.44269504f);
    slope2[0] = (_Float16)SLOPE;
    slope2[1] = (_Float16)SLOPE;

    int beg = offsets[node], end = offsets[node + 1];
    int deg = end - beg;                                     // uniform per group
    int d0 = __builtin_amdgcn_readlane(deg, 0);
    int d1 = __builtin_amdgcn_readlane(deg, 16);
    int d2 = __builtin_amdgcn_readlane(deg, 32);
    int d3 = __builtin_amdgcn_readlane(deg, 48);
    int m01 = d0 > d1 ? d0 : d1, m23 = d2 > d3 ? d2 : d3;
    int degMax = m01 > m23 ? m01 : m23;
    int n01 = d0 < d1 ? d0 : d1, n23 = d2 < d3 ? d2 : d3;
    int degMin = n01 < n23 ? n01 : n23;

    float s = 0.f;
    float acc[8] = {0.f, 0.f, 0.f, 0.f, 0.f, 0.f, 0.f, 0.f};
    const char* xlb = (const char*)xlh;

    // branchless clamped row-offset load for block starting at c0 (always
    // in-bounds: cnt<=0 collapses to sorted16[beg], which exists).
    auto load_off = [&](int c0) -> unsigned {
        int rem = deg - c0;
        int cnt = rem > 16 ? 16 : rem;
        int cl  = cnt > 0 ? (hl < cnt ? hl : cnt - 1) : 0;
        int pos = cnt > 0 ? beg + c0 + cl : beg;
        return ((unsigned)sorted16[pos]) << 8;             // fp16 row byte offset
    };

    unsigned off = load_off(0);
    for (int c0 = 0; c0 < degMax; c0 += 16) {
        unsigned off_nx = load_off(c0 + 16);   // issued BEFORE this block's work
        int rem = deg - c0;
        int cnt = rem > 16 ? 16 : rem;                       // may be <=0 on short group
        int jmax = degMax - c0; if (jmax > 16) jmax = 16;
        int nfull = degMin - c0; if (nfull > 16) nfull = 16; if (nfull < 0) nfull = 0;
        int j = 0;
        for (; j + 8 <= nfull; j += 8)                       // unmasked fast path
            edge_block<8, false>(j, idx_bp, off, laneoff, xlb, xr8, att4, slope2,
                                 cnt, s, acc);
        for (; j + 4 <= nfull; j += 4)
            edge_block<4, false>(j, idx_bp, off, laneoff, xlb, xr8, att4, slope2,
                                 cnt, s, acc);
        for (; j + 4 <= jmax; j += 4)                        // masked mid
            edge_block<4, true>(j, idx_bp, off, laneoff, xlb, xr8, att4, slope2,
                                cnt, s, acc);
        for (; j < jmax; ++j)                                // masked scalar tail
            edge_block<1, true>(j, idx_bp, off, laneoff, xlb, xr8, att4, slope2,
                                cnt, s, acc);
        off = off_nx;
    }

    float inv = 1.f / s;                 // every node has >=1 edge (self-loop)
    float4 b0 = *(const float4*)&bias_l[hl * 8];
    float4 b1 = *(const float4*)&bias_l[hl * 8 + 4];
    float o[8];
    o[0] = acc[0] * inv + b0.x; o[1] = acc[1] * inv + b0.y;
    o[2] = acc[2] * inv + b0.z; o[3] = acc[3] * inv + b0.w;
    o[4] = acc[4] * inv + b1.x; o[5] = acc[5] * inv + b1.y;
    o[6] = acc[6] * inv + b1.z; o[7] = acc[7] * inv + b1.w;
    float sum = ((o[0] + o[1]) + (o[2] + o[3])) + ((o[4] + o[5]) + (o[6] + o[7]));
    float sq  = ((o[0] * o[0] + o[1] * o[1]) + (o[2] * o[2] + o[3] * o[3]))
              + ((o[4] * o[4] + o[5] * o[5]) + (o[6] * o[6] + o[7] * o[7]));
    #pragma unroll
    for (int msk = 1; msk < 16; msk <<= 1) {   // stays inside the 16-lane group
        sum += __shfl_xor(sum, msk);
        sq  += __shfl_xor(sq, msk);
    }
    float mu   = sum * (1.f / 128.f);
    float var  = sq * (1.f / 128.f) - mu * mu;
    float rstd = rsqrtf(var + LN_EPS);
    float4 g0 = *(const float4*)&gamma_l[hl * 8];
    float4 g1 = *(const float4*)&gamma_l[hl * 8 + 4];
    float4 e0 = *(const float4*)&beta_l[hl * 8];
    float4 e1 = *(const float4*)&beta_l[hl * 8 + 4];
    float gam[8] = {g0.x, g0.y, g0.z, g0.w, g1.x, g1.y, g1.z, g1.w};
    float bet[8] = {e0.x, e0.y, e0.z, e0.w, e1.x, e1.y, e1.z, e1.w};
    size_t di = (size_t)node * D + hl * 8;
    float4 h0 = *(const float4*)&hin[di];
    float4 h1 = *(const float4*)&hin[di + 4];
    float hv[8] = {h0.x, h0.y, h0.z, h0.w, h1.x, h1.y, h1.z, h1.w};
    float y[8];
    #pragma unroll
    for (int i = 0; i < 8; ++i) {
        float t = (o[i] - mu) * rstd * gam[i] + bet[i];
        t = t > 0.f ? t : __expf(t) - 1.f;   // ELU (alpha=1)
        y[i] = hv[i] + t;
    }
    float4 w0 = make_float4(y[0], y[1], y[2], y[3]);
    float4 w1 = make_float4(y[4], y[5], y[6], y[7]);
    *(float4*)&hout[di]     = w0;
    *(float4*)&hout[di + 4] = w1;
    half8 h16v;
    #pragma unroll
    for (int i = 0; i < 8; ++i) h16v[i] = (_Float16)y[i];
    *(half8*)&h16out[di] = h16v;            // fp16 copy for next layer's gemm
}

// ---------------------------------------------------------------------------

extern "C" void kernel_launch(void* const* d_in, const int* in_sizes, int n_in,
                              void* d_out, int out_size, void* d_ws, size_t ws_size,
                              hipStream_t stream) {
    const float* x     = (const float*)d_in[0];
    const float* Wl    = (const float*)d_in[1];
    const float* Wr    = (const float*)d_in[2];
    const float* att   = (const float*)d_in[3];
    const float* bias  = (const float*)d_in[4];
    const float* gamma = (const float*)d_in[5];
    const float* beta  = (const float*)d_in[6];
    const int*   ei    = (const int*)d_in[7];
    float* h = (float*)d_out;

    char* ws = (char*)d_ws;
    _Float16* xlh = (_Float16*)ws;   ws += (size_t)N_NODES * D * sizeof(_Float16);
    _Float16* xrh = (_Float16*)ws;   ws += (size_t)N_NODES * D * sizeof(_Float16);
    _Float16* h16 = (_Float16*)ws;   ws += (size_t)N_NODES * D * sizeof(_Float16);
    _Float16* Wfrag = (_Float16*)ws; ws += (size_t)3 * 4096 * 8 * sizeof(_Float16);
    int* offsets = (int*)ws;         ws += (size_t)(N_NODES + 4) * sizeof(int);
    int* counts  = (int*)ws;         ws += (size_t)N_NODES * sizeof(int);
    int* bsum    = (int*)ws;         ws += 64 * sizeof(int);
    int* bpre    = (int*)ws;         ws += 64 * sizeof(int);
    int* blockhist = (int*)ws;       ws += (size_t)SCAN_BLOCKS * 256 * sizeof(int);
    int* perm    = (int*)ws;         ws += (size_t)N_NODES * sizeof(int);
    int* rank    = (int*)ws;         ws += (size_t)ETOT * sizeof(int);
    unsigned short* sorted16 = (unsigned short*)ws;   // ETOT u16

    // W fragments + CSR by dst + degree-sort perm (shared by all 3 layers)
    wfrag_kernel<<<48, 256, 0, stream>>>(Wl, Wr, Wfrag);
    (void)hipMemsetAsync(counts, 0, (size_t)N_NODES * sizeof(int), stream);
    rank_hist_kernel<<<(ETOT + 255) / 256, 256, 0, stream>>>(ei, counts, rank);
    scan1_kernel<<<SCAN_BLOCKS, 1024, 0, stream>>>(counts, offsets, bsum, blockhist);
    scan2_kernel<<<1, 256, 0, stream>>>(bsum, bpre, blockhist);
    scan3_kernel<<<SCAN_BLOCKS, 1024, 0, stream>>>(offsets, bpre, counts, blockhist, perm);
    scatter_kernel<<<(ETOT + 255) / 256, 256, 0, stream>>>(ei, offsets, rank, sorted16);

    int gat_waves  = (N_NODES + 3) / 4;                       // 4 nodes / wave
    int gat_blocks = (gat_waves * 64 + 255) / 256;            // 3125
    for (int l = 0; l < L; ++l) {
        const float* hin = (l == 0) ? x : h;
        if (l == 0)
            gemm_mfma_kernel<false><<<(N_NODES + 63) / 64, 256, 0, stream>>>(
                x, Wfrag + (size_t)l * 4096 * 8, xlh, xrh);
        else
            gemm_mfma_kernel<true><<<(N_NODES + 63) / 64, 256, 0, stream>>>(
                h16, Wfrag + (size_t)l * 4096 * 8, xlh, xrh);
        gat_node_kernel<<<gat_blocks, 256, 0, stream>>>(
            xlh, xrh, offsets, sorted16, perm,
            att + (size_t)l * D, bias + (size_t)l * D,
            gamma + (size_t)l * D, beta + (size_t)l * D, hin, h, h16);
    }
}

// Round 11
// 320.616 us; speedup vs baseline: 1.6661x; 1.0189x over previous
//
#include <hip/hip_runtime.h>
#include <hip/hip_fp16.h>
#include <math.h>

#define N_NODES 50000
#define N_EDGES 800000
#define D 128
#define L 3
#define SLOPE 0.2f
#define LN_EPS 1e-5f
#define ETOT (N_EDGES + N_NODES)
#define SCAN_BLOCKS ((N_NODES + 1023) / 1024)   // 49

typedef _Float16 half8 __attribute__((ext_vector_type(8)));
typedef _Float16 h4v  __attribute__((ext_vector_type(4)));
typedef _Float16 h2v  __attribute__((ext_vector_type(2)));
typedef float f32x4 __attribute__((ext_vector_type(4)));

// ---------------- CSR build (once per call, reused for all layers) ----------

__global__ void rank_hist_kernel(const int* __restrict__ ei, int* __restrict__ counts,
                                 int* __restrict__ rank) {
    int idx = blockIdx.x * blockDim.x + threadIdx.x;
    if (idx >= ETOT) return;
    int d = (idx < N_EDGES) ? ei[N_EDGES + idx] : (idx - N_EDGES);
    rank[idx] = atomicAdd(&counts[d], 1);
}

// scan1 also builds the per-block degree histogram (fused deg_hist).
__global__ __launch_bounds__(1024) void scan1_kernel(const int* __restrict__ counts,
                                                     int* __restrict__ offsets,
                                                     int* __restrict__ bsum,
                                                     int* __restrict__ blockhist) {
    __shared__ int wsum[16];
    __shared__ int lh[256];
    int tid = threadIdx.x;
    if (tid < 256) lh[tid] = 0;
    __syncthreads();
    int lane = tid & 63, w = tid >> 6;
    int i = blockIdx.x * 1024 + tid;
    int v = (i < N_NODES) ? counts[i] : 0;
    if (i < N_NODES) {
        int d = v; if (d > 255) d = 255;
        atomicAdd(&lh[d], 1);                  // LDS histogram, cheap
    }
    int sc = v;
    #pragma unroll
    for (int off = 1; off < 64; off <<= 1) {
        int u = __shfl_up(sc, off);
        if (lane >= off) sc += u;
    }
    if (lane == 63) wsum[w] = sc;
    __syncthreads();
    if (w == 0) {
        int t2 = (lane < 16) ? wsum[lane] : 0;
        #pragma unroll
        for (int off = 1; off < 16; off <<= 1) {
            int u = __shfl_up(t2, off);
            if (lane >= off) t2 += u;
        }
        if (lane < 16) wsum[lane] = t2;
    }
    __syncthreads();
    int wpref = (w == 0) ? 0 : wsum[w - 1];
    if (i < N_NODES) offsets[i] = wpref + sc - v;      // block-local exclusive
    if (tid == 0) bsum[blockIdx.x] = wsum[15];
    __syncthreads();
    if (tid < 256) blockhist[blockIdx.x * 256 + tid] = lh[tid];
}

// scan2 also turns blockhist into global scatter bases (fused deg_scan).
__global__ __launch_bounds__(256) void scan2_kernel(const int* __restrict__ bsum,
                                                    int* __restrict__ bpre,
                                                    int* __restrict__ blockhist) {
    int tid = threadIdx.x;
    if (tid < 64) {
        int lane = tid;
        int v = (lane < SCAN_BLOCKS) ? bsum[lane] : 0;
        int sc = v;
        #pragma unroll
        for (int off = 1; off < 64; off <<= 1) {
            int u = __shfl_up(sc, off);
            if (lane >= off) sc += u;
        }
        if (lane < SCAN_BLOCKS) bpre[lane] = sc - v;   // exclusive
    }
    int d = tid;
    int run = 0;
    #pragma unroll 1
    for (int b = 0; b < SCAN_BLOCKS; ++b) {
        int c = blockhist[b * 256 + d];
        blockhist[b * 256 + d] = run;
        run += c;
    }
    __shared__ int wsum[4];
    int lane = d & 63, w = d >> 6;
    int sc = run;
    #pragma unroll
    for (int off = 1; off < 64; off <<= 1) {
        int u = __shfl_up(sc, off);
        if (lane >= off) sc += u;
    }
    if (lane == 63) wsum[w] = sc;
    __syncthreads();
    int wpre = 0;
    #pragma unroll
    for (int k = 0; k < 4; ++k) wpre += (k < w) ? wsum[k] : 0;
    int binbase = wpre + sc - run;                  // exclusive over bins
    #pragma unroll 1
    for (int b = 0; b < SCAN_BLOCKS; ++b)
        blockhist[b * 256 + d] += binbase;
}

// scan3 also scatters the degree-sorted node permutation (fused deg_scatter).
__global__ __launch_bounds__(1024) void scan3_kernel(int* __restrict__ offsets,
                                                     const int* __restrict__ bpre,
                                                     const int* __restrict__ counts,
                                                     const int* __restrict__ blockhist,
                                                     int* __restrict__ perm) {
    __shared__ int lh[256];
    int tid = threadIdx.x;
    if (tid < 256) lh[tid] = 0;
    __syncthreads();
    int i = blockIdx.x * 1024 + tid;
    if (i < N_NODES) {
        offsets[i] += bpre[blockIdx.x];
        int d = counts[i]; if (d > 255) d = 255;
        int r = atomicAdd(&lh[d], 1);               // LDS rank within block+bin
        perm[blockhist[blockIdx.x * 256 + d] + r] = i;
    }
    if (i == 0) offsets[N_NODES] = ETOT;
}

__global__ void scatter_kernel(const int* __restrict__ ei, const int* __restrict__ offsets,
                               const int* __restrict__ rank,
                               unsigned short* __restrict__ sorted16) {
    int idx = blockIdx.x * blockDim.x + threadIdx.x;
    if (idx >= ETOT) return;
    int s, d;
    if (idx < N_EDGES) { s = ei[idx]; d = ei[N_EDGES + idx]; }
    else               { s = d = idx - N_EDGES; }
    sorted16[offsets[d] + rank[idx]] = (unsigned short)s;   // no atomic
}

// ---------------- W -> fp16 MFMA B-fragment precompute ---------------------

__global__ __launch_bounds__(256) void wfrag_kernel(const float* __restrict__ Wl,
                                                    const float* __restrict__ Wr,
                                                    _Float16* __restrict__ Wfrag) {
    int u = blockIdx.x * 256 + threadIdx.x;   // 3*2*4*8*64 = 12288 slots
    if (u >= 3 * 4096) return;
    int lane = u & 63, nt = (u >> 6) & 7, kt = (u >> 9) & 3, y = (u >> 11) & 1, l = u >> 12;
    int r = lane & 15, q = lane >> 4;
    const float* W = (y ? Wr : Wl) + (size_t)l * D * D;
    half8 v;
    #pragma unroll
    for (int j = 0; j < 8; ++j)
        v[j] = (_Float16)W[(kt * 32 + q * 8 + j) * D + nt * 16 + r];
    *(half8*)&Wfrag[(size_t)u * 8] = v;
}

// ---------------- MFMA GEMM: xl,xr (fp16) = h @ {Wl,Wr} --------------------
// NEW: 8-wave (512-thread) blocks. Wave owns (y, feature-QUARTER): bfrag 8
// half8 (32 VGPR), acc 8 f32x4 (32 VGPR) -> ~2x resident waves vs the 4-wave
// version (6256 total, ~24/CU) to hide the stage->sync->MFMA latency chain.
// Operand-swapped MFMA (verified r7-r10): lane&15 = node row, 4 acc regs = 4
// consecutive features -> 8-B h4v stores. Same LDS layout as before.

template<bool AHALF>
__global__ __launch_bounds__(512) void gemm_mfma_kernel(
        const void* __restrict__ hsrc, const _Float16* __restrict__ WfragL,
        _Float16* __restrict__ xlh, _Float16* __restrict__ xrh) {
    __shared__ half8 Afrag[1024];   // [ntile][kt*64 + q*16 + r], 16 KB
    int t = threadIdx.x;
    int row0 = blockIdx.x * 64;
    int w = t >> 6, lane = t & 63;
    int y = w >> 2, q4 = w & 3;     // wave's W-matrix (l/r) and feature quarter

    // ---- W fragments: issue first (latency hidden under A staging) ----
    half8 bfrag[8];                 // [kt][f], compile-time indexed only
    #pragma unroll
    for (int kt = 0; kt < 4; ++kt)
        #pragma unroll
        for (int f = 0; f < 2; ++f) {
            int nt = q4 * 2 + f;
            bfrag[kt * 2 + f] =
                *(const half8*)&WfragL[(size_t)(((y * 4 + kt) * 8 + nt) * 64 + lane) * 8];
        }

    // ---- A staging: 512 threads stage 1024 half8 slots (2 each) ----
    #pragma unroll
    for (int uu = 0; uu < 2; ++uu) {
        int u = t + uu * 512;
        int i = u >> 8, rem = u & 255;
        int kt = rem >> 6, q = (rem >> 4) & 3, r = rem & 15;
        int kc = kt * 4 + q;                  // 8-half chunk index
        int row = row0 + i * 16 + r;
        half8 v = {};
        if (row < N_NODES) {
            if constexpr (AHALF) {
                const _Float16* h16 = (const _Float16*)hsrc;
                v = *(const half8*)&h16[(size_t)row * D + kc * 8];
            } else {
                const float* p = &((const float*)hsrc)[(size_t)row * D + kc * 8];
                float4 f0 = *(const float4*)p;
                float4 f1 = *(const float4*)(p + 4);
                v[0] = (_Float16)f0.x; v[1] = (_Float16)f0.y;
                v[2] = (_Float16)f0.z; v[3] = (_Float16)f0.w;
                v[4] = (_Float16)f1.x; v[5] = (_Float16)f1.y;
                v[6] = (_Float16)f1.z; v[7] = (_Float16)f1.w;
            }
        }
        Afrag[u] = v;                         // [i][kt*64 + q*16 + r]
    }
    __syncthreads();

    // ---- compute: 4 node-tiles x 4 kt x 2 feature-tiles, operands swapped ----
    f32x4 acc[8];                   // [f][ntile]
    #pragma unroll
    for (int i = 0; i < 8; ++i) acc[i] = (f32x4){0.f, 0.f, 0.f, 0.f};
    #pragma unroll
    for (int ntile = 0; ntile < 4; ++ntile) {
        #pragma unroll
        for (int kt = 0; kt < 4; ++kt) {
            half8 a = Afrag[ntile * 256 + kt * 64 + lane];
            #pragma unroll
            for (int f = 0; f < 2; ++f)
                acc[f * 4 + ntile] = __builtin_amdgcn_mfma_f32_16x16x32_f16(
                    bfrag[kt * 2 + f], a, acc[f * 4 + ntile], 0, 0, 0);
        }
    }

    // ---- store: lane holds 4 consecutive feats of node ntile*16+(lane&15) ----
    _Float16* out = y ? xrh : xlh;
    int nr = lane & 15, fq = lane >> 4;
    #pragma unroll
    for (int ntile = 0; ntile < 4; ++ntile) {
        int row = row0 + ntile * 16 + nr;
        if (row < N_NODES) {
            #pragma unroll
            for (int f = 0; f < 2; ++f) {
                int fb = q4 * 32 + f * 16 + fq * 4;
                h4v v4;
                v4[0] = (_Float16)acc[f * 4 + ntile][0];
                v4[1] = (_Float16)acc[f * 4 + ntile][1];
                v4[2] = (_Float16)acc[f * 4 + ntile][2];
                v4[3] = (_Float16)acc[f * 4 + ntile][3];
                *(h4v*)&out[(size_t)row * D + fb] = v4;
            }
        }
    }
}

// ---------------- per-node GATv2 + softmax + LN + ELU + residual -----------
// FOUR nodes per wave (degree-sorted, LPT descending dispatch); 16 lanes/node,
// 8 ch/lane; DPP pair reduction; ds_bpermute broadcast; dwordx4 gathers;
// c0-level sorted16 prefetch. Byte-identical to the passing round-10 kernel.

__device__ __forceinline__ float pair_reduce2(float p) {
    int t;
    t = __builtin_amdgcn_update_dpp(0, __float_as_int(p), 0xB1, 0xF, 0xF, true);  // quad [1,0,3,2]
    p += __int_as_float(t);
    return p;
}

__device__ __forceinline__ float logit8(half8 v, half8 xr, const h2v* att4, h2v slope2) {
    float p = 0.f;
    #pragma unroll
    for (int i = 0; i < 4; ++i) {
        h2v a; a[0] = v[2 * i];  a[1] = v[2 * i + 1];
        h2v b; b[0] = xr[2 * i]; b[1] = xr[2 * i + 1];
        h2v f  = a + b;                                   // v_pk_add_f16
        h2v lf = __builtin_elementwise_max(f, f * slope2);
        p = __builtin_amdgcn_fdot2(lf, att4[i], p, false);
    }
    return p;
}

template<int KUN, bool MASK>
__device__ __forceinline__ void edge_block(
        int j, int idx_bp, unsigned off, unsigned laneoff, const char* xlb,
        half8 xr8, const h2v* att4, h2v slope2, int cnt,
        float& s, float* acc) {
    half8 vs[KUN];
    #pragma unroll
    for (int k = 0; k < KUN; ++k) {
        int o = __builtin_amdgcn_ds_bpermute(idx_bp + 4 * (j + k), (int)off);
        vs[k] = *(const half8*)(xlb + ((unsigned)o + laneoff));   // dwordx4
    }
    #pragma unroll
    for (int k = 0; k < KUN; ++k) {
        float p = logit8(vs[k], xr8, att4, slope2);
        p = pair_reduce2(p);
        float e = __builtin_amdgcn_exp2f(p);
        if (MASK) e = (j + k < cnt) ? e : 0.f;
        s += e;
        #pragma unroll
        for (int i = 0; i < 8; ++i)
            acc[i] = fmaf(e, (float)vs[k][i], acc[i]);            // v_fma_mix
    }
}

__global__ __launch_bounds__(256) void gat_node_kernel(
        const _Float16* __restrict__ xlh, const _Float16* __restrict__ xrh,
        const int* __restrict__ offsets, const unsigned short* __restrict__ sorted16,
        const int* __restrict__ perm,
        const float* __restrict__ att_l, const float* __restrict__ bias_l,
        const float* __restrict__ gamma_l, const float* __restrict__ beta_l,
        const float* __restrict__ hin, float* __restrict__ hout,
        _Float16* __restrict__ h16out) {
    int wid = (blockIdx.x * blockDim.x + threadIdx.x) >> 6;   // wave id
    if (wid * 4 >= N_NODES) return;
    int lane = threadIdx.x & 63;
    int g = lane >> 4, hl = lane & 15;         // group (node select), sub-lane
    int node = perm[N_NODES - 4 - wid * 4 + g];   // LPT: descending degree
    unsigned laneoff = hl * 16u;               // byte offset of this lane's 8 halves
    int idx_bp = g << 6;                       // bpermute byte base: lane 16*g

    half8 xr8 = *(const half8*)&xrh[(size_t)node * D + hl * 8];
    float4 af0 = *(const float4*)&att_l[hl * 8];
    float4 af1 = *(const float4*)&att_l[hl * 8 + 4];
    h2v att4[4], slope2;
    att4[0][0] = (_Float16)(af0.x * 1.44269504f);  // pre-scale by log2(e)
    att4[0][1] = (_Float16)(af0.y * 1.44269504f);
    att4[1][0] = (_Float16)(af0.z * 1.44269504f);
    att4[1][1] = (_Float16)(af0.w * 1.44269504f);
    att4[2][0] = (_Float16)(af1.x * 1.44269504f);
    att4[2][1] = (_Float16)(af1.y * 1.44269504f);
    att4[3][0] = (_Float16)(af1.z * 1.44269504f);
    att4[3][1] = (_Float16)(af1.w * 1.44269504f);
    slope2[0] = (_Float16)SLOPE;
    slope2[1] = (_Float16)SLOPE;

    int beg = offsets[node], end = offsets[node + 1];
    int deg = end - beg;                                     // uniform per group
    int d0 = __builtin_amdgcn_readlane(deg, 0);
    int d1 = __builtin_amdgcn_readlane(deg, 16);
    int d2 = __builtin_amdgcn_readlane(deg, 32);
    int d3 = __builtin_amdgcn_readlane(deg, 48);
    int m01 = d0 > d1 ? d0 : d1, m23 = d2 > d3 ? d2 : d3;
    int degMax = m01 > m23 ? m01 : m23;
    int n01 = d0 < d1 ? d0 : d1, n23 = d2 < d3 ? d2 : d3;
    int degMin = n01 < n23 ? n01 : n23;

    float s = 0.f;
    float acc[8] = {0.f, 0.f, 0.f, 0.f, 0.f, 0.f, 0.f, 0.f};
    const char* xlb = (const char*)xlh;

    auto load_off = [&](int c0) -> unsigned {
        int rem = deg - c0;
        int cnt = rem > 16 ? 16 : rem;
        int cl  = cnt > 0 ? (hl < cnt ? hl : cnt - 1) : 0;
        int pos = cnt > 0 ? beg + c0 + cl : beg;
        return ((unsigned)sorted16[pos]) << 8;             // fp16 row byte offset
    };

    unsigned off = load_off(0);
    for (int c0 = 0; c0 < degMax; c0 += 16) {
        unsigned off_nx = load_off(c0 + 16);   // issued BEFORE this block's work
        int rem = deg - c0;
        int cnt = rem > 16 ? 16 : rem;                       // may be <=0 on short group
        int jmax = degMax - c0; if (jmax > 16) jmax = 16;
        int nfull = degMin - c0; if (nfull > 16) nfull = 16; if (nfull < 0) nfull = 0;
        int j = 0;
        for (; j + 8 <= nfull; j += 8)                       // unmasked fast path
            edge_block<8, false>(j, idx_bp, off, laneoff, xlb, xr8, att4, slope2,
                                 cnt, s, acc);
        for (; j + 4 <= nfull; j += 4)
            edge_block<4, false>(j, idx_bp, off, laneoff, xlb, xr8, att4, slope2,
                                 cnt, s, acc);
        for (; j + 4 <= jmax; j += 4)                        // masked mid
            edge_block<4, true>(j, idx_bp, off, laneoff, xlb, xr8, att4, slope2,
                                cnt, s, acc);
        for (; j < jmax; ++j)                                // masked scalar tail
            edge_block<1, true>(j, idx_bp, off, laneoff, xlb, xr8, att4, slope2,
                                cnt, s, acc);
        off = off_nx;
    }

    float inv = 1.f / s;                 // every node has >=1 edge (self-loop)
    float4 b0 = *(const float4*)&bias_l[hl * 8];
    float4 b1 = *(const float4*)&bias_l[hl * 8 + 4];
    float o[8];
    o[0] = acc[0] * inv + b0.x; o[1] = acc[1] * inv + b0.y;
    o[2] = acc[2] * inv + b0.z; o[3] = acc[3] * inv + b0.w;
    o[4] = acc[4] * inv + b1.x; o[5] = acc[5] * inv + b1.y;
    o[6] = acc[6] * inv + b1.z; o[7] = acc[7] * inv + b1.w;
    float sum = ((o[0] + o[1]) + (o[2] + o[3])) + ((o[4] + o[5]) + (o[6] + o[7]));
    float sq  = ((o[0] * o[0] + o[1] * o[1]) + (o[2] * o[2] + o[3] * o[3]))
              + ((o[4] * o[4] + o[5] * o[5]) + (o[6] * o[6] + o[7] * o[7]));
    #pragma unroll
    for (int msk = 1; msk < 16; msk <<= 1) {   // stays inside the 16-lane group
        sum += __shfl_xor(sum, msk);
        sq  += __shfl_xor(sq, msk);
    }
    float mu   = sum * (1.f / 128.f);
    float var  = sq * (1.f / 128.f) - mu * mu;
    float rstd = rsqrtf(var + LN_EPS);
    float4 g0 = *(const float4*)&gamma_l[hl * 8];
    float4 g1 = *(const float4*)&gamma_l[hl * 8 + 4];
    float4 e0 = *(const float4*)&beta_l[hl * 8];
    float4 e1 = *(const float4*)&beta_l[hl * 8 + 4];
    float gam[8] = {g0.x, g0.y, g0.z, g0.w, g1.x, g1.y, g1.z, g1.w};
    float bet[8] = {e0.x, e0.y, e0.z, e0.w, e1.x, e1.y, e1.z, e1.w};
    size_t di = (size_t)node * D + hl * 8;
    float4 h0 = *(const float4*)&hin[di];
    float4 h1 = *(const float4*)&hin[di + 4];
    float hv[8] = {h0.x, h0.y, h0.z, h0.w, h1.x, h1.y, h1.z, h1.w};
    float y[8];
    #pragma unroll
    for (int i = 0; i < 8; ++i) {
        float t = (o[i] - mu) * rstd * gam[i] + bet[i];
        t = t > 0.f ? t : __expf(t) - 1.f;   // ELU (alpha=1)
        y[i] = hv[i] + t;
    }
    float4 w0 = make_float4(y[0], y[1], y[2], y[3]);
    float4 w1 = make_float4(y[4], y[5], y[6], y[7]);
    *(float4*)&hout[di]     = w0;
    *(float4*)&hout[di + 4] = w1;
    half8 h16v;
    #pragma unroll
    for (int i = 0; i < 8; ++i) h16v[i] = (_Float16)y[i];
    *(half8*)&h16out[di] = h16v;            // fp16 copy for next layer's gemm
}

// ---------------------------------------------------------------------------

extern "C" void kernel_launch(void* const* d_in, const int* in_sizes, int n_in,
                              void* d_out, int out_size, void* d_ws, size_t ws_size,
                              hipStream_t stream) {
    const float* x     = (const float*)d_in[0];
    const float* Wl    = (const float*)d_in[1];
    const float* Wr    = (const float*)d_in[2];
    const float* att   = (const float*)d_in[3];
    const float* bias  = (const float*)d_in[4];
    const float* gamma = (const float*)d_in[5];
    const float* beta  = (const float*)d_in[6];
    const int*   ei    = (const int*)d_in[7];
    float* h = (float*)d_out;

    char* ws = (char*)d_ws;
    _Float16* xlh = (_Float16*)ws;   ws += (size_t)N_NODES * D * sizeof(_Float16);
    _Float16* xrh = (_Float16*)ws;   ws += (size_t)N_NODES * D * sizeof(_Float16);
    _Float16* h16 = (_Float16*)ws;   ws += (size_t)N_NODES * D * sizeof(_Float16);
    _Float16* Wfrag = (_Float16*)ws; ws += (size_t)3 * 4096 * 8 * sizeof(_Float16);
    int* offsets = (int*)ws;         ws += (size_t)(N_NODES + 4) * sizeof(int);
    int* counts  = (int*)ws;         ws += (size_t)N_NODES * sizeof(int);
    int* bsum    = (int*)ws;         ws += 64 * sizeof(int);
    int* bpre    = (int*)ws;         ws += 64 * sizeof(int);
    int* blockhist = (int*)ws;       ws += (size_t)SCAN_BLOCKS * 256 * sizeof(int);
    int* perm    = (int*)ws;         ws += (size_t)N_NODES * sizeof(int);
    int* rank    = (int*)ws;         ws += (size_t)ETOT * sizeof(int);
    unsigned short* sorted16 = (unsigned short*)ws;   // ETOT u16

    // W fragments + CSR by dst + degree-sort perm (shared by all 3 layers)
    wfrag_kernel<<<48, 256, 0, stream>>>(Wl, Wr, Wfrag);
    (void)hipMemsetAsync(counts, 0, (size_t)N_NODES * sizeof(int), stream);
    rank_hist_kernel<<<(ETOT + 255) / 256, 256, 0, stream>>>(ei, counts, rank);
    scan1_kernel<<<SCAN_BLOCKS, 1024, 0, stream>>>(counts, offsets, bsum, blockhist);
    scan2_kernel<<<1, 256, 0, stream>>>(bsum, bpre, blockhist);
    scan3_kernel<<<SCAN_BLOCKS, 1024, 0, stream>>>(offsets, bpre, counts, blockhist, perm);
    scatter_kernel<<<(ETOT + 255) / 256, 256, 0, stream>>>(ei, offsets, rank, sorted16);

    int gat_waves  = (N_NODES + 3) / 4;                       // 4 nodes / wave
    int gat_blocks = (gat_waves * 64 + 255) / 256;            // 3125
    for (int l = 0; l < L; ++l) {
        const float* hin = (l == 0) ? x : h;
        if (l == 0)
            gemm_mfma_kernel<false><<<(N_NODES + 63) / 64, 512, 0, stream>>>(
                x, Wfrag + (size_t)l * 4096 * 8, xlh, xrh);
        else
            gemm_mfma_kernel<true><<<(N_NODES + 63) / 64, 512, 0, stream>>>(
                h16, Wfrag + (size_t)l * 4096 * 8, xlh, xrh);
        gat_node_kernel<<<gat_blocks, 256, 0, stream>>>(
            xlh, xrh, offsets, sorted16, perm,
            att + (size_t)l * D, bias + (size_t)l * D,
            gamma + (size_t)l * D, beta + (size_t)l * D, hin, h, h16);
    }
}